// Round 2
// baseline (590.105 us; speedup 1.0000x reference)
//
#include <hip/hip_runtime.h>
#include <math.h>

#define VOCAB 119547
#define NB    64
#define NS    512
#define NH    768
#define M_TOT (NB * NS)   // 32768

// ---------------------------------------------------------------------------
// Zero two float4 regions (sparse output + importance workspace).
// Harness poisons d_out/d_ws with 0xAA, so we must init ourselves.
// ---------------------------------------------------------------------------
__global__ void zero_regions(float4* __restrict__ a, long na4,
                             float4* __restrict__ b, long nb4) {
    long i = (long)blockIdx.x * blockDim.x + threadIdx.x;
    long stride = (long)gridDim.x * blockDim.x;
    const float4 z = make_float4(0.f, 0.f, 0.f, 0.f);
    for (long j = i; j < na4; j += stride) a[j] = z;
    for (long j = i; j < nb4; j += stride) b[j] = z;
}

// ---------------------------------------------------------------------------
// Fused GEMM + relu + W2-dot.
//   For a 64x128 tile of (X @ W1): apply +b1, relu, * W2[col], reduce over
//   the 128 cols, atomicAdd per-row partials into imp[M].
// Tiling: BM=64, BN=128, BK=16; 256 threads; micro-tile 8 rows x 4 cols.
// ---------------------------------------------------------------------------
__global__ __launch_bounds__(256) void gemm_importance(
    const float* __restrict__ X,    // [M_TOT, NH]
    const float* __restrict__ W1,   // [NH, NH]
    const float* __restrict__ b1,   // [NH]
    const float* __restrict__ W2v,  // [NH]
    float* __restrict__ imp)        // [M_TOT] (accumulated)
{
    __shared__ float As[16][64];    // A stored transposed: As[k][row]
    __shared__ float Bs[16][128];

    const int tid = threadIdx.x;
    const int m0 = blockIdx.x * 64;
    const int n0 = blockIdx.y * 128;
    const int tx = tid & 31;        // col group: cols tx*4 .. tx*4+3
    const int ty = tid >> 5;        // row group: rows ty*8 .. ty*8+7

    float acc[8][4];
#pragma unroll
    for (int r = 0; r < 8; ++r)
#pragma unroll
        for (int c = 0; c < 4; ++c) acc[r][c] = 0.f;

    // A-tile load mapping: 64 rows x 16 cols = 256 float4, one per thread.
    const int arow = tid >> 2;          // 0..63
    const int ac   = (tid & 3) * 4;     // 0,4,8,12
    const float* Xp = X + (long)(m0 + arow) * NH + ac;

    for (int k0 = 0; k0 < NH; k0 += 16) {
        // ---- stage A (transposed) ----
        float4 av = *(const float4*)(Xp + k0);
        As[ac + 0][arow] = av.x;
        As[ac + 1][arow] = av.y;
        As[ac + 2][arow] = av.z;
        As[ac + 3][arow] = av.w;
        // ---- stage B: 16 rows x 128 cols = 512 float4, two per thread ----
        {
            int f = tid;
            int br = f >> 5, bc = (f & 31) * 4;
            *(float4*)&Bs[br][bc] = *(const float4*)&W1[(long)(k0 + br) * NH + n0 + bc];
            f = tid + 256;
            br = f >> 5; bc = (f & 31) * 4;
            *(float4*)&Bs[br][bc] = *(const float4*)&W1[(long)(k0 + br) * NH + n0 + bc];
        }
        __syncthreads();

#pragma unroll
        for (int k = 0; k < 16; ++k) {
            float4 a0 = *(const float4*)&As[k][ty * 8];
            float4 a1 = *(const float4*)&As[k][ty * 8 + 4];
            float4 bv = *(const float4*)&Bs[k][tx * 4];
            float a[8] = {a0.x, a0.y, a0.z, a0.w, a1.x, a1.y, a1.z, a1.w};
            float bb[4] = {bv.x, bv.y, bv.z, bv.w};
#pragma unroll
            for (int r = 0; r < 8; ++r)
#pragma unroll
                for (int c = 0; c < 4; ++c)
                    acc[r][c] = fmaf(a[r], bb[c], acc[r][c]);
        }
        __syncthreads();
    }

    // ---- epilogue: +b1, relu, *W2, reduce cols, atomicAdd per row ----
    float b1v[4], w2v[4];
#pragma unroll
    for (int c = 0; c < 4; ++c) {
        int col = n0 + tx * 4 + c;
        b1v[c] = b1[col];
        w2v[c] = W2v[col];
    }
#pragma unroll
    for (int r = 0; r < 8; ++r) {
        float p = 0.f;
#pragma unroll
        for (int c = 0; c < 4; ++c) {
            float h = fmaxf(acc[r][c] + b1v[c], 0.f);
            p = fmaf(h, w2v[c], p);
        }
        // reduce across the 32 tx lanes (xor masks stay within the group)
#pragma unroll
        for (int mdel = 16; mdel >= 1; mdel >>= 1) p += __shfl_xor(p, mdel);
        if (tx == 0) atomicAdd(&imp[m0 + ty * 8 + r], p);
    }
}

// ---------------------------------------------------------------------------
// Finalize: token_weights + scatter-max into sparse_repr.
// All weights >= 0, buffer init 0 -> uint atomicMax is exact for IEEE floats.
// NOTE: input_ids is int64 in the reference but the harness stores integer
// inputs as int32 on device -> cast to const int*.
// ---------------------------------------------------------------------------
__global__ void finalize(const float* __restrict__ imp,
                         const float* __restrict__ b2,
                         const int* __restrict__ mask,
                         const int* __restrict__ ids,
                         float* __restrict__ tw_out,
                         float* __restrict__ sparse) {
    int i = blockIdx.x * blockDim.x + threadIdx.x;
    if (i >= M_TOT) return;
    float v = imp[i] + b2[0];
    v = fmaxf(v, 0.f);
    float tw = log1pf(v) * (float)mask[i];
    tw_out[i] = tw;
    int b  = i >> 9;               // i / 512
    int id = ids[i];
    unsigned int* addr = (unsigned int*)&sparse[(long)b * VOCAB + id];
    atomicMax(addr, __float_as_uint(tw));
}

// ---------------------------------------------------------------------------
extern "C" void kernel_launch(void* const* d_in, const int* in_sizes, int n_in,
                              void* d_out, int out_size, void* d_ws, size_t ws_size,
                              hipStream_t stream) {
    const float* X    = (const float*)d_in[0];
    const int*   ids  = (const int*)d_in[1];    // int64 in ref -> int32 on device
    const int*   mask = (const int*)d_in[2];
    const float* W1   = (const float*)d_in[3];
    const float* b1   = (const float*)d_in[4];
    const float* W2   = (const float*)d_in[5];
    const float* b2   = (const float*)d_in[6];

    float* sparse = (float*)d_out;                       // [64, VOCAB]
    float* tw_out = sparse + (long)NB * VOCAB;           // [64, 512]
    float* imp    = (float*)d_ws;                        // [32768] floats

    zero_regions<<<2048, 256, 0, stream>>>(
        (float4*)sparse, (long)NB * VOCAB / 4,
        (float4*)imp, M_TOT / 4);

    dim3 grid(M_TOT / 64, NH / 128);
    gemm_importance<<<grid, 256, 0, stream>>>(X, W1, b1, W2, imp);

    finalize<<<M_TOT / 256, 256, 0, stream>>>(imp, b2, mask, ids, tw_out, sparse);
}

// Round 4
// 244.505 us; speedup vs baseline: 2.4135x; 2.4135x over previous
//
#include <hip/hip_runtime.h>
#include <math.h>
#include <stdint.h>

#define VOCAB 119547
#define NB    64
#define NS    512
#define NH    768
#define M_TOT (NB * NS)   // 32768

typedef _Float16 half8_t __attribute__((ext_vector_type(8)));
typedef _Float16 half4_t __attribute__((ext_vector_type(4)));
typedef float f32x4 __attribute__((ext_vector_type(4)));

// ---------------------------------------------------------------------------
// global -> LDS async 16B copy (DMA). LDS dest is wave-uniform base + lane*16,
// global src is per-lane. (guide §5; m97 pattern)
// ---------------------------------------------------------------------------
__device__ __forceinline__ void gload_lds16(const void* g, void* l) {
    __builtin_amdgcn_global_load_lds(
        (const __attribute__((address_space(1))) uint32_t*)g,
        (__attribute__((address_space(3))) uint32_t*)l, 16, 0, 0);
}

// ---------------------------------------------------------------------------
// prep: zero sparse+imp, convert X -> fp16, convert+transpose W1 -> W1T fp16.
// ---------------------------------------------------------------------------
__global__ void prep(const float* __restrict__ X, const float* __restrict__ W1,
                     float4* __restrict__ sparse4, float* __restrict__ imp4_,
                     _Float16* __restrict__ Xh, _Float16* __restrict__ W1T) {
    long i = (long)blockIdx.x * blockDim.x + threadIdx.x;
    long stride = (long)gridDim.x * blockDim.x;
    const float4 z = make_float4(0.f, 0.f, 0.f, 0.f);
    const long nsp4 = (long)NB * VOCAB / 4;          // 1,912,752
    for (long j = i; j < nsp4; j += stride) sparse4[j] = z;
    float4* imp4 = (float4*)imp4_;
    for (long j = i; j < M_TOT / 4; j += stride) imp4[j] = z;
    // X: fp32 -> fp16, 4 at a time
    const long nx4 = (long)M_TOT * NH / 4;           // 6,291,456
    const float4* X4 = (const float4*)X;
    half4_t* Xh4 = (half4_t*)Xh;
    for (long j = i; j < nx4; j += stride) {
        float4 v = X4[j];
        half4_t h;
        h[0] = (_Float16)v.x; h[1] = (_Float16)v.y;
        h[2] = (_Float16)v.z; h[3] = (_Float16)v.w;
        Xh4[j] = h;
    }
    // W1T[n][k] = (f16) W1[k][n]; 4 consecutive k per thread -> 8B stores
    const long nw4 = (long)NH * NH / 4;              // 147,456
    half4_t* W1T4 = (half4_t*)W1T;
    for (long j = i; j < nw4; j += stride) {
        int n  = (int)(j / (NH / 4));
        int k4 = (int)(j % (NH / 4)) * 4;
        half4_t h;
#pragma unroll
        for (int q = 0; q < 4; ++q) h[q] = (_Float16)W1[(long)(k4 + q) * NH + n];
        W1T4[j] = h;
    }
}

// ---------------------------------------------------------------------------
// FP16 MFMA GEMM fused with relu + W2-dot epilogue.
// 128x128 tile, BK=32, 4 waves (2x2), each wave 64x64 = 4x4 frags of 16x16x32.
// A = Xh [M][768] row-major; B = W1T [N=768 rows][K=768] row-major.
// LDS linear with chunk-XOR swizzle c^=((r>>1)&3) applied at the global src
// (rule #21: gload_lds writes linearly; swizzle source + read identically).
// ---------------------------------------------------------------------------
__global__ __launch_bounds__(256) void gemm_f16(
    const _Float16* __restrict__ Xh,
    const _Float16* __restrict__ W1T,
    const float* __restrict__ b1,
    const float* __restrict__ W2v,
    float* __restrict__ imp)
{
    __shared__ __align__(16) _Float16 As[128 * 32];
    __shared__ __align__(16) _Float16 Bs[128 * 32];

    const int tid  = threadIdx.x;
    const int lane = tid & 63;
    const int wid  = tid >> 6;
    const int wm   = wid >> 1;      // wave row 0..1
    const int wn   = wid & 1;       // wave col 0..1

    // XCD-bijective swizzle: nwg = 1536 = 8 * 192. n-tile fastest so 6
    // consecutive wg share the A-tile within one XCD's L2.
    const int bid = blockIdx.x;
    const int wg  = (bid & 7) * 192 + (bid >> 3);
    const int nt  = wg % 6;
    const int mt  = wg / 6;
    const int m0  = mt * 128;
    const int n0  = nt * 128;

    // staging: 512 chunks of 16B per operand; thread t handles chunks t, t+256
    const int c0 = tid, c1 = tid + 256;
    const int r0 = c0 >> 2, r1 = c1 >> 2;
    const int sk0 = ((c0 & 3) ^ ((r0 >> 1) & 3)) * 8;   // swizzled global k-chunk
    const int sk1 = ((c1 & 3) ^ ((r1 >> 1) & 3)) * 8;
    const _Float16* gA0 = Xh  + (long)(m0 + r0) * NH + sk0;
    const _Float16* gA1 = Xh  + (long)(m0 + r1) * NH + sk1;
    const _Float16* gB0 = W1T + (long)(n0 + r0) * NH + sk0;
    const _Float16* gB1 = W1T + (long)(n0 + r1) * NH + sk1;
    _Float16* lA0 = As + c0 * 8;  _Float16* lA1 = As + c1 * 8;
    _Float16* lB0 = Bs + c0 * 8;  _Float16* lB1 = Bs + c1 * 8;

    // frag read offsets: lane l -> row lr = l&15, k-seg ls = l>>4.
    // read seg s2 = ls ^ ((lr>>1)&3)  (base rows are multiples of 16, so the
    // swizzle term depends only on lr). 2-way banks -> conflict-free.
    const int lr = lane & 15;
    const int ls = lane >> 4;
    const int s2 = ls ^ ((lr >> 1) & 3);
    int offA[4], offB[4];
#pragma unroll
    for (int f = 0; f < 4; ++f) {
        offA[f] = (wm * 64 + f * 16 + lr) * 32 + s2 * 8;
        offB[f] = (wn * 64 + f * 16 + lr) * 32 + s2 * 8;
    }

    f32x4 acc[4][4];
#pragma unroll
    for (int a = 0; a < 4; ++a)
#pragma unroll
        for (int b = 0; b < 4; ++b) acc[a][b] = (f32x4){0.f, 0.f, 0.f, 0.f};

#pragma unroll 1
    for (int kk = 0; kk < NH / 32; ++kk) {
        gload_lds16(gA0, lA0);
        gload_lds16(gA1, lA1);
        gload_lds16(gB0, lB0);
        gload_lds16(gB1, lB1);
        gA0 += 32; gA1 += 32; gB0 += 32; gB1 += 32;
        __syncthreads();   // compiler drains vmcnt(0) -> staged data visible

        half8_t af[4], bf[4];
#pragma unroll
        for (int f = 0; f < 4; ++f) af[f] = *(const half8_t*)(As + offA[f]);
#pragma unroll
        for (int f = 0; f < 4; ++f) bf[f] = *(const half8_t*)(Bs + offB[f]);
#pragma unroll
        for (int a = 0; a < 4; ++a)
#pragma unroll
            for (int b = 0; b < 4; ++b)
                acc[a][b] = __builtin_amdgcn_mfma_f32_16x16x32_f16(
                    af[a], bf[b], acc[a][b], 0, 0, 0);
        __syncthreads();   // all waves done reading before next-step DMA
    }

    // ---- epilogue: +b1, relu, *W2, reduce over n, atomicAdd per row ----
    // C/D layout (m89): col = lane&15 (n), row = (lane>>4)*4 + reg (m).
    float b1v[4], w2v[4];
#pragma unroll
    for (int f = 0; f < 4; ++f) {
        int col = n0 + wn * 64 + f * 16 + lr;
        b1v[f] = b1[col];
        w2v[f] = W2v[col];
    }
#pragma unroll
    for (int a = 0; a < 4; ++a)
#pragma unroll
        for (int reg = 0; reg < 4; ++reg) {
            float p = 0.f;
#pragma unroll
            for (int f = 0; f < 4; ++f) {
                float h = fmaxf(acc[a][f][reg] + b1v[f], 0.f);
                p = fmaf(h, w2v[f], p);
            }
            p += __shfl_xor(p, 1);
            p += __shfl_xor(p, 2);
            p += __shfl_xor(p, 4);
            p += __shfl_xor(p, 8);
            if (lr == 0) {
                int row = m0 + wm * 64 + a * 16 + ls * 4 + reg;
                atomicAdd(&imp[row], p);
            }
        }
}

// ---------------------------------------------------------------------------
// finalize: token_weights + scatter-max (uint atomicMax exact for >=0 floats)
// ---------------------------------------------------------------------------
__global__ void finalize(const float* __restrict__ imp,
                         const float* __restrict__ b2,
                         const int* __restrict__ mask,
                         const int* __restrict__ ids,
                         float* __restrict__ tw_out,
                         float* __restrict__ sparse) {
    int i = blockIdx.x * blockDim.x + threadIdx.x;
    if (i >= M_TOT) return;
    float v = fmaxf(imp[i] + b2[0], 0.f);
    float tw = log1pf(v) * (float)mask[i];
    tw_out[i] = tw;
    int b  = i >> 9;
    int id = ids[i];
    unsigned int* addr = (unsigned int*)&sparse[(long)b * VOCAB + id];
    atomicMax(addr, __float_as_uint(tw));
}

// ======================= fallback fp32 path (proven) =======================
__global__ void zero_regions(float4* __restrict__ a, long na4,
                             float4* __restrict__ b, long nb4) {
    long i = (long)blockIdx.x * blockDim.x + threadIdx.x;
    long stride = (long)gridDim.x * blockDim.x;
    const float4 z = make_float4(0.f, 0.f, 0.f, 0.f);
    for (long j = i; j < na4; j += stride) a[j] = z;
    for (long j = i; j < nb4; j += stride) b[j] = z;
}

__global__ __launch_bounds__(256) void gemm_importance(
    const float* __restrict__ X, const float* __restrict__ W1,
    const float* __restrict__ b1, const float* __restrict__ W2v,
    float* __restrict__ imp)
{
    __shared__ float As_[16][64];
    __shared__ float Bs_[16][128];
    const int tid = threadIdx.x;
    const int m0 = blockIdx.x * 64, n0 = blockIdx.y * 128;
    const int tx = tid & 31, ty = tid >> 5;
    float acc[8][4];
#pragma unroll
    for (int r = 0; r < 8; ++r)
#pragma unroll
        for (int c = 0; c < 4; ++c) acc[r][c] = 0.f;
    const int arow = tid >> 2, ac = (tid & 3) * 4;
    const float* Xp = X + (long)(m0 + arow) * NH + ac;
    for (int k0 = 0; k0 < NH; k0 += 16) {
        float4 av = *(const float4*)(Xp + k0);
        As_[ac + 0][arow] = av.x; As_[ac + 1][arow] = av.y;
        As_[ac + 2][arow] = av.z; As_[ac + 3][arow] = av.w;
        int f = tid, br = f >> 5, bc = (f & 31) * 4;
        *(float4*)&Bs_[br][bc] = *(const float4*)&W1[(long)(k0 + br) * NH + n0 + bc];
        f = tid + 256; br = f >> 5; bc = (f & 31) * 4;
        *(float4*)&Bs_[br][bc] = *(const float4*)&W1[(long)(k0 + br) * NH + n0 + bc];
        __syncthreads();
#pragma unroll
        for (int k = 0; k < 16; ++k) {
            float4 a0 = *(const float4*)&As_[k][ty * 8];
            float4 a1 = *(const float4*)&As_[k][ty * 8 + 4];
            float4 bv = *(const float4*)&Bs_[k][tx * 4];
            float a[8] = {a0.x, a0.y, a0.z, a0.w, a1.x, a1.y, a1.z, a1.w};
            float bb[4] = {bv.x, bv.y, bv.z, bv.w};
#pragma unroll
            for (int r = 0; r < 8; ++r)
#pragma unroll
                for (int c = 0; c < 4; ++c)
                    acc[r][c] = fmaf(a[r], bb[c], acc[r][c]);
        }
        __syncthreads();
    }
    float b1v[4], w2v[4];
#pragma unroll
    for (int c = 0; c < 4; ++c) {
        int col = n0 + tx * 4 + c;
        b1v[c] = b1[col]; w2v[c] = W2v[col];
    }
#pragma unroll
    for (int r = 0; r < 8; ++r) {
        float p = 0.f;
#pragma unroll
        for (int c = 0; c < 4; ++c)
            p = fmaf(fmaxf(acc[r][c] + b1v[c], 0.f), w2v[c], p);
#pragma unroll
        for (int mdel = 16; mdel >= 1; mdel >>= 1) p += __shfl_xor(p, mdel);
        if (tx == 0) atomicAdd(&imp[m0 + ty * 8 + r], p);
    }
}

// ---------------------------------------------------------------------------
extern "C" void kernel_launch(void* const* d_in, const int* in_sizes, int n_in,
                              void* d_out, int out_size, void* d_ws, size_t ws_size,
                              hipStream_t stream) {
    const float* X    = (const float*)d_in[0];
    const int*   ids  = (const int*)d_in[1];   // int64 in ref -> int32 on device
    const int*   mask = (const int*)d_in[2];
    const float* W1   = (const float*)d_in[3];
    const float* b1   = (const float*)d_in[4];
    const float* W2   = (const float*)d_in[5];
    const float* b2   = (const float*)d_in[6];

    float* sparse = (float*)d_out;                    // [64, VOCAB]
    float* tw_out = sparse + (long)NB * VOCAB;        // [64, 512]
    float* imp    = (float*)d_ws;                     // [32768] f32 at offset 0

    const size_t impB = (size_t)M_TOT * 4;            // 131072
    const size_t XhB  = (size_t)M_TOT * NH * 2;       // 50,331,648
    const size_t W1TB = (size_t)NH * NH * 2;          // 1,179,648
    const size_t need = impB + XhB + W1TB;

    if (ws_size >= need) {
        _Float16* Xh  = (_Float16*)((char*)d_ws + impB);
        _Float16* W1T = (_Float16*)((char*)d_ws + impB + XhB);
        prep<<<2048, 256, 0, stream>>>(X, W1, (float4*)sparse, imp, Xh, W1T);
        gemm_f16<<<(M_TOT / 128) * (NH / 128), 256, 0, stream>>>(
            Xh, W1T, b1, W2, imp);
        finalize<<<M_TOT / 256, 256, 0, stream>>>(imp, b2, mask, ids, tw_out, sparse);
    } else {
        zero_regions<<<2048, 256, 0, stream>>>(
            (float4*)sparse, (long)NB * VOCAB / 4, (float4*)imp, M_TOT / 4);
        dim3 grid(M_TOT / 64, NH / 128);
        gemm_importance<<<grid, 256, 0, stream>>>(X, W1, b1, W2, imp);
        finalize<<<M_TOT / 256, 256, 0, stream>>>(imp, b2, mask, ids, tw_out, sparse);
    }
}